// Round 2
// baseline (240.733 us; speedup 1.0000x reference)
//
#include <hip/hip_runtime.h>
#include <hip/hip_bf16.h>
#include <stdint.h>

// Problem constants (fixed by reference file)
#define U_DIM 2048
#define T_DIM 200
#define Q_DIM 4096
#define K_DIM 16
#define H_DIM 256
#define N_UT  (U_DIM * T_DIM)   // 409600
#define N_ROWS (Q_DIM * 2)      // 8192 distinct (q, resp) MLP inputs
#define UK    (U_DIM * K_DIM)   // 32768 scan chains

typedef float f4 __attribute__((ext_vector_type(4)));

__device__ __forceinline__ float gelu_f(float x) {
    // exact gelu (approximate=False): 0.5*x*(1+erf(x/sqrt(2)))
    return 0.5f * x * (1.0f + erff(x * 0.70710678118654752440f));
}

// ---------------------------------------------------------------------------
// Kernel 0: probe kmap's storage layout.
// jax bool_ may arrive 1-byte-packed or upcast to int32. If byte-packed,
// uint32 words hold 4 bools (P(word<=1) = 0.75^3 = 0.42 -> across 1024 words
// some word > 1 with certainty). If int32, every word is 0 or 1.
// flag = 1 -> byte layout, 0 -> int32 layout. Deterministic (fixed input).
// ---------------------------------------------------------------------------
__global__ __launch_bounds__(64) void probe_kernel(const uint32_t* __restrict__ kmap_w,
                                                   uint32_t* __restrict__ flag) {
    int tid = threadIdx.x;
    uint32_t any = 0;
    #pragma unroll
    for (int i = 0; i < 16; ++i) any |= (kmap_w[tid + 64 * i] > 1u) ? 1u : 0u;
    uint64_t b = __ballot(any != 0);
    if (tid == 0) *flag = (b != 0) ? 1u : 0u;
}

// ---------------------------------------------------------------------------
// Kernel 1: pack kmap (Q,K) bool -> 16-bit mask, honoring probed layout
// ---------------------------------------------------------------------------
__global__ void pack_kmap_kernel(const uint8_t* __restrict__ kmap,
                                 const uint32_t* __restrict__ flag,
                                 uint32_t* __restrict__ mask_tab) {
    int q = blockIdx.x * blockDim.x + threadIdx.x;
    if (q >= Q_DIM) return;
    uint32_t m = 0;
    if (*flag) {
        // 1 byte per element
        const uint32_t* p = (const uint32_t*)(kmap + (size_t)q * K_DIM);
        #pragma unroll
        for (int w = 0; w < 4; ++w) {
            uint32_t v = p[w];
            #pragma unroll
            for (int b = 0; b < 4; ++b)
                m |= (((v >> (8 * b)) & 0xffu) ? 1u : 0u) << (4 * w + b);
        }
    } else {
        // int32 per element
        const int* ki = (const int*)kmap + (size_t)q * K_DIM;
        #pragma unroll
        for (int k = 0; k < K_DIM; ++k)
            m |= (ki[k] ? 1u : 0u) << k;
    }
    mask_tab[q] = m;
}

// ---------------------------------------------------------------------------
// Kernel 2: fp32 MLP over the 8192 distinct rows (q, r) -> mu_tab, lmda_tab
// One 64-thread block handles G=8 rows. Thread owns 4 columns (j=4*tid..+3).
// h1 staged transposed in LDS (padded stride 12 floats), layer2 = register-
// tiled 8x4 outer product, layer3 reduced wave-wide via shfl_xor.
// ---------------------------------------------------------------------------
__global__ __launch_bounds__(64) void mlp_table_kernel(
    const float* __restrict__ diff_mu, const float* __restrict__ disc_mu,
    const float* __restrict__ W1, const float* __restrict__ b1,
    const float* __restrict__ W2, const float* __restrict__ b2,
    const float* __restrict__ W3, const float* __restrict__ b3,
    float* __restrict__ mu_tab, float* __restrict__ lmda_tab)
{
    const int G = 8;
    __shared__ float h1t[H_DIM][12];  // [input-col i][row g], pad 8->12
    int tid = threadIdx.x;
    int row0 = blockIdx.x * G;

    // ---- layer 1: h1 = gelu(inp @ W1 + b1), inp = [td, ts, r]
    f4 w1a = *(const f4*)&W1[0 * H_DIM + 4 * tid];
    f4 w1b = *(const f4*)&W1[1 * H_DIM + 4 * tid];
    f4 w1c = *(const f4*)&W1[2 * H_DIM + 4 * tid];
    f4 bb1 = *(const f4*)&b1[4 * tid];
    #pragma unroll
    for (int g = 0; g < G; ++g) {
        int row = row0 + g;
        int q = row >> 1;
        float rr = (float)(row & 1);
        float td = diff_mu[q];
        float ts = disc_mu[q];
        #pragma unroll
        for (int c = 0; c < 4; ++c) {
            float x = td * w1a[c] + ts * w1b[c] + rr * w1c[c] + bb1[c];
            h1t[4 * tid + c][g] = gelu_f(x);
        }
    }
    __syncthreads();

    // ---- layer 2: acc[g][c] = b2 + sum_i h1[g][i] * W2[i][4tid+c]
    float acc[G][4];
    f4 bb2 = *(const f4*)&b2[4 * tid];
    #pragma unroll
    for (int g = 0; g < G; ++g) {
        acc[g][0] = bb2[0]; acc[g][1] = bb2[1]; acc[g][2] = bb2[2]; acc[g][3] = bb2[3];
    }
    #pragma unroll 4
    for (int i = 0; i < H_DIM; ++i) {
        f4 wv = *(const f4*)&W2[i * H_DIM + 4 * tid];
        f4 hA = *(const f4*)&h1t[i][0];   // rows 0..3 (uniform addr -> broadcast)
        f4 hB = *(const f4*)&h1t[i][4];   // rows 4..7
        #pragma unroll
        for (int c = 0; c < 4; ++c) {
            acc[0][c] += hA[0] * wv[c];
            acc[1][c] += hA[1] * wv[c];
            acc[2][c] += hA[2] * wv[c];
            acc[3][c] += hA[3] * wv[c];
            acc[4][c] += hB[0] * wv[c];
            acc[5][c] += hB[1] * wv[c];
            acc[6][c] += hB[2] * wv[c];
            acc[7][c] += hB[3] * wv[c];
        }
    }

    // ---- layer 3: poten[c] = gelu(sum_j h2[j]*W3[j][c] + b3[c])
    // W3 is (H,2) row-major; thread's 4 j's are elements 8tid..8tid+7
    f4 w3lo = *(const f4*)&W3[8 * tid];       // (j0,c0)(j0,c1)(j1,c0)(j1,c1)
    f4 w3hi = *(const f4*)&W3[8 * tid + 4];   // (j2,c0)(j2,c1)(j3,c0)(j3,c1)
    float p0[G], p1[G];
    #pragma unroll
    for (int g = 0; g < G; ++g) {
        float h0 = gelu_f(acc[g][0]);
        float h1v = gelu_f(acc[g][1]);
        float h2v = gelu_f(acc[g][2]);
        float h3v = gelu_f(acc[g][3]);
        p0[g] = h0 * w3lo[0] + h1v * w3lo[2] + h2v * w3hi[0] + h3v * w3hi[2];
        p1[g] = h0 * w3lo[1] + h1v * w3lo[3] + h2v * w3hi[1] + h3v * w3hi[3];
    }
    #pragma unroll
    for (int g = 0; g < G; ++g) {
        #pragma unroll
        for (int off = 1; off < 64; off <<= 1) {
            p0[g] += __shfl_xor(p0[g], off);
            p1[g] += __shfl_xor(p1[g], off);
        }
    }
    if (tid == 0) {
        float bb30 = b3[0], bb31 = b3[1];
        #pragma unroll
        for (int g = 0; g < G; ++g) {
            int row = row0 + g;
            float mu = gelu_f(p0[g] + bb30);
            float lv = gelu_f(p1[g] + bb31);
            mu_tab[row] = mu;
            lmda_tab[row] = expf(-fmaxf(lv, 1e-8f));
        }
    }
}

// ---------------------------------------------------------------------------
// Kernel 3: gather per (u,t) into (T,U)-layout streams so the scan kernels
// have purely affine (prefetchable) loads.
// ---------------------------------------------------------------------------
__global__ void gather_kernel(
    const int* __restrict__ q_id, const float* __restrict__ resp,
    const float* __restrict__ mu_tab, const float* __restrict__ lmda_tab,
    const uint32_t* __restrict__ mask_tab,
    float* __restrict__ mu_s, float* __restrict__ lmda_s,
    uint16_t* __restrict__ m16_s)
{
    int n = blockIdx.x * blockDim.x + threadIdx.x;   // n = t*U + u
    if (n >= N_UT) return;
    int u = n & (U_DIM - 1);
    int t = n >> 11;
    int q = q_id[u * T_DIM + t];
    float rv = resp[u * T_DIM + t];
    int idx = q * 2 + (rv != 0.0f ? 1 : 0);
    mu_s[n]   = mu_tab[idx];
    lmda_s[n] = lmda_tab[idx];
    m16_s[n]  = (uint16_t)mask_tab[q];
}

// ---------------------------------------------------------------------------
// Kernel 4: backward scan (t = T-1 .. 0), one thread per (u,k) chain.
// alphas[(t,u,k)] stored to workspace (26.2 MB).
// ---------------------------------------------------------------------------
__global__ __launch_bounds__(64) void bwd_kernel(
    const float* __restrict__ mu_s, const float* __restrict__ lmda_s,
    const uint16_t* __restrict__ m16_s, float* __restrict__ alphas)
{
    int u = blockIdx.x * 4 + (threadIdx.x >> 4);
    int k = threadIdx.x & 15;
    float alpha = 0.0f, beta = 0.0f;
    int b = (T_DIM - 1) * U_DIM + u;
    float l_n = lmda_s[b];
    float mu_n = mu_s[b];
    uint32_t m_n = m16_s[b];
    float* aptr = alphas + u * 16 + k;
    #pragma unroll 4
    for (int t = T_DIM - 1; t >= 0; --t) {
        float l = l_n, mu_ = mu_n;
        uint32_t m = m_n;
        if (t > 0) {  // 1-deep prefetch of next iteration's (affine) loads
            int bb = (t - 1) * U_DIM + u;
            l_n = lmda_s[bb]; mu_n = mu_s[bb]; m_n = m16_s[bb];
        }
        // LMDA_THETA = 1
        float an = (l + alpha) / (1.0f + l + alpha);
        float bn = (l * mu_ + an * l * beta) / (l + an * l);
        if ((m >> k) & 1) { alpha = an; beta = bn; }
        aptr[t * UK] = alpha;   // post-update value, index t (scan reverse=True)
    }
}

// ---------------------------------------------------------------------------
// Kernel 5: forward scan (t = 0 .. T-1) + reduction over K -> out (U,T)
// ---------------------------------------------------------------------------
__global__ __launch_bounds__(64) void fwd_kernel(
    const float* __restrict__ mu_s, const float* __restrict__ lmda_s,
    const uint16_t* __restrict__ m16_s, const float* __restrict__ alphas,
    float* __restrict__ out)
{
    int u = blockIdx.x * 4 + (threadIdx.x >> 4);
    int k = threadIdx.x & 15;
    float ability = 0.0f;
    float l_n = lmda_s[u];
    float mu_n = mu_s[u];
    uint32_t m_n = m16_s[u];
    const float* aptr = alphas + u * 16 + k;
    float a_n = aptr[UK];   // alphas[t=1]
    #pragma unroll 4
    for (int t = 0; t < T_DIM; ++t) {
        float l = l_n, mu_ = mu_n;
        uint32_t m = m_n;
        float a_nxt = a_n;
        if (t < T_DIM - 1) {
            int bb = (t + 1) * U_DIM + u;
            l_n = lmda_s[bb]; mu_n = mu_s[bb]; m_n = m16_s[bb];
            a_n = (t < T_DIM - 2) ? aptr[(t + 2) * UK] : 0.0f;
        }
        // b_nxt = a_nxt; LMDA_THETA = 1
        float num = ability + mu_ * l + a_nxt * a_nxt;
        float den = 1.0f + l + a_nxt;
        float mt = num / den;
        bool msk = (m >> k) & 1;
        ability = msk ? mt : ability;
        float s = msk ? ability : 0.0f;   // ab * mf
        float c = msk ? 1.0f : 0.0f;      // mf
        #pragma unroll
        for (int off = 1; off < 16; off <<= 1) {
            s += __shfl_xor(s, off);
            c += __shfl_xor(c, off);
        }
        if (k == 0) out[u * T_DIM + t] = s / fmaxf(c, 1e-8f);
    }
}

// ---------------------------------------------------------------------------
extern "C" void kernel_launch(void* const* d_in, const int* in_sizes, int n_in,
                              void* d_out, int out_size, void* d_ws, size_t ws_size,
                              hipStream_t stream) {
    // setup_inputs order: mask, q_id, kmap, resp, diff_mu, disc_mu, W1,b1,W2,b2,W3,b3
    // mask (d_in[0]) is UNUSED by the reference computation.
    const int*     q_id    = (const int*)d_in[1];
    const uint8_t* kmap    = (const uint8_t*)d_in[2];   // layout probed at runtime
    const float*   resp    = (const float*)d_in[3];
    const float*   diff_mu = (const float*)d_in[4];
    const float*   disc_mu = (const float*)d_in[5];
    const float*   W1      = (const float*)d_in[6];
    const float*   b1      = (const float*)d_in[7];
    const float*   W2      = (const float*)d_in[8];
    const float*   b2      = (const float*)d_in[9];
    const float*   W3      = (const float*)d_in[10];
    const float*   b3      = (const float*)d_in[11];
    float* out = (float*)d_out;

    // workspace layout (~29 MB total)
    char* w = (char*)d_ws;
    float* mu_tab      = (float*)w;      w += (size_t)N_ROWS * 4;
    float* lmda_tab    = (float*)w;      w += (size_t)N_ROWS * 4;
    uint32_t* mask_tab = (uint32_t*)w;   w += (size_t)Q_DIM * 4;
    uint32_t* flag     = (uint32_t*)w;   w += 64;   // padded for alignment
    float* mu_s        = (float*)w;      w += (size_t)N_UT * 4;
    float* lmda_s      = (float*)w;      w += (size_t)N_UT * 4;
    uint16_t* m16_s    = (uint16_t*)w;   w += (size_t)N_UT * 2;
    float* alphas      = (float*)w;      w += (size_t)N_UT * K_DIM * 4;

    hipLaunchKernelGGL(probe_kernel, dim3(1), dim3(64), 0, stream,
                       (const uint32_t*)kmap, flag);
    hipLaunchKernelGGL(pack_kmap_kernel, dim3(Q_DIM / 256), dim3(256), 0, stream,
                       kmap, flag, mask_tab);
    hipLaunchKernelGGL(mlp_table_kernel, dim3(N_ROWS / 8), dim3(64), 0, stream,
                       diff_mu, disc_mu, W1, b1, W2, b2, W3, b3, mu_tab, lmda_tab);
    hipLaunchKernelGGL(gather_kernel, dim3(N_UT / 256), dim3(256), 0, stream,
                       q_id, resp, mu_tab, lmda_tab, mask_tab, mu_s, lmda_s, m16_s);
    hipLaunchKernelGGL(bwd_kernel, dim3(UK / 64), dim3(64), 0, stream,
                       mu_s, lmda_s, m16_s, alphas);
    hipLaunchKernelGGL(fwd_kernel, dim3(UK / 64), dim3(64), 0, stream,
                       mu_s, lmda_s, m16_s, alphas, out);
}

// Round 3
// 167.171 us; speedup vs baseline: 1.4400x; 1.4400x over previous
//
#include <hip/hip_runtime.h>
#include <hip/hip_bf16.h>
#include <stdint.h>

// Problem constants (fixed by reference file)
#define U_DIM 2048
#define T_DIM 200
#define Q_DIM 4096
#define K_DIM 16
#define H_DIM 256
#define N_UT  (U_DIM * T_DIM)   // 409600
#define N_ROWS (Q_DIM * 2)      // 8192 distinct (q, resp) MLP inputs
#define UK    (U_DIM * K_DIM)   // 32768 scan chains

typedef float f4 __attribute__((ext_vector_type(4)));

__device__ __forceinline__ float gelu_f(float x) {
    // exact gelu (approximate=False): 0.5*x*(1+erf(x/sqrt(2)))
    return 0.5f * x * (1.0f + erff(x * 0.70710678118654752440f));
}

// ---------------------------------------------------------------------------
// Kernel 0: probe kmap's storage layout (byte-bools vs int32-bools).
// If byte-packed, some uint32 word among the first 1024 is >1 with certainty
// (P(word<=1)=0.75^3 per word). If int32, every word is 0/1. Deterministic.
// ---------------------------------------------------------------------------
__global__ __launch_bounds__(64) void probe_kernel(const uint32_t* __restrict__ kmap_w,
                                                   uint32_t* __restrict__ flag) {
    int tid = threadIdx.x;
    uint32_t any = 0;
    #pragma unroll
    for (int i = 0; i < 16; ++i) any |= (kmap_w[tid + 64 * i] > 1u) ? 1u : 0u;
    uint64_t b = __ballot(any != 0);
    if (tid == 0) *flag = (b != 0) ? 1u : 0u;
}

// ---------------------------------------------------------------------------
// Kernel 1: pack kmap (Q,K) bool -> 16-bit mask, honoring probed layout
// ---------------------------------------------------------------------------
__global__ void pack_kmap_kernel(const uint8_t* __restrict__ kmap,
                                 const uint32_t* __restrict__ flag,
                                 uint32_t* __restrict__ mask_tab) {
    int q = blockIdx.x * blockDim.x + threadIdx.x;
    if (q >= Q_DIM) return;
    uint32_t m = 0;
    if (*flag) {
        const uint32_t* p = (const uint32_t*)(kmap + (size_t)q * K_DIM);
        #pragma unroll
        for (int w = 0; w < 4; ++w) {
            uint32_t v = p[w];
            #pragma unroll
            for (int b = 0; b < 4; ++b)
                m |= (((v >> (8 * b)) & 0xffu) ? 1u : 0u) << (4 * w + b);
        }
    } else {
        const int* ki = (const int*)kmap + (size_t)q * K_DIM;
        #pragma unroll
        for (int k = 0; k < K_DIM; ++k)
            m |= (ki[k] ? 1u : 0u) << k;
    }
    mask_tab[q] = m;
}

// ---------------------------------------------------------------------------
// Kernel 2: fp32 MLP over the 8192 distinct rows (q, r) -> mu_tab, lmda_tab
// (unchanged from R1 — isolating this round's change to the scan fusion)
// ---------------------------------------------------------------------------
__global__ __launch_bounds__(64) void mlp_table_kernel(
    const float* __restrict__ diff_mu, const float* __restrict__ disc_mu,
    const float* __restrict__ W1, const float* __restrict__ b1,
    const float* __restrict__ W2, const float* __restrict__ b2,
    const float* __restrict__ W3, const float* __restrict__ b3,
    float* __restrict__ mu_tab, float* __restrict__ lmda_tab)
{
    const int G = 8;
    __shared__ float h1t[H_DIM][12];  // [input-col i][row g], pad 8->12
    int tid = threadIdx.x;
    int row0 = blockIdx.x * G;

    f4 w1a = *(const f4*)&W1[0 * H_DIM + 4 * tid];
    f4 w1b = *(const f4*)&W1[1 * H_DIM + 4 * tid];
    f4 w1c = *(const f4*)&W1[2 * H_DIM + 4 * tid];
    f4 bb1 = *(const f4*)&b1[4 * tid];
    #pragma unroll
    for (int g = 0; g < G; ++g) {
        int row = row0 + g;
        int q = row >> 1;
        float rr = (float)(row & 1);
        float td = diff_mu[q];
        float ts = disc_mu[q];
        #pragma unroll
        for (int c = 0; c < 4; ++c) {
            float x = td * w1a[c] + ts * w1b[c] + rr * w1c[c] + bb1[c];
            h1t[4 * tid + c][g] = gelu_f(x);
        }
    }
    __syncthreads();

    float acc[G][4];
    f4 bb2 = *(const f4*)&b2[4 * tid];
    #pragma unroll
    for (int g = 0; g < G; ++g) {
        acc[g][0] = bb2[0]; acc[g][1] = bb2[1]; acc[g][2] = bb2[2]; acc[g][3] = bb2[3];
    }
    #pragma unroll 4
    for (int i = 0; i < H_DIM; ++i) {
        f4 wv = *(const f4*)&W2[i * H_DIM + 4 * tid];
        f4 hA = *(const f4*)&h1t[i][0];
        f4 hB = *(const f4*)&h1t[i][4];
        #pragma unroll
        for (int c = 0; c < 4; ++c) {
            acc[0][c] += hA[0] * wv[c];
            acc[1][c] += hA[1] * wv[c];
            acc[2][c] += hA[2] * wv[c];
            acc[3][c] += hA[3] * wv[c];
            acc[4][c] += hB[0] * wv[c];
            acc[5][c] += hB[1] * wv[c];
            acc[6][c] += hB[2] * wv[c];
            acc[7][c] += hB[3] * wv[c];
        }
    }

    f4 w3lo = *(const f4*)&W3[8 * tid];
    f4 w3hi = *(const f4*)&W3[8 * tid + 4];
    float p0[G], p1[G];
    #pragma unroll
    for (int g = 0; g < G; ++g) {
        float h0 = gelu_f(acc[g][0]);
        float h1v = gelu_f(acc[g][1]);
        float h2v = gelu_f(acc[g][2]);
        float h3v = gelu_f(acc[g][3]);
        p0[g] = h0 * w3lo[0] + h1v * w3lo[2] + h2v * w3hi[0] + h3v * w3hi[2];
        p1[g] = h0 * w3lo[1] + h1v * w3lo[3] + h2v * w3hi[1] + h3v * w3hi[3];
    }
    #pragma unroll
    for (int g = 0; g < G; ++g) {
        #pragma unroll
        for (int off = 1; off < 64; off <<= 1) {
            p0[g] += __shfl_xor(p0[g], off);
            p1[g] += __shfl_xor(p1[g], off);
        }
    }
    if (tid == 0) {
        float bb30 = b3[0], bb31 = b3[1];
        #pragma unroll
        for (int g = 0; g < G; ++g) {
            int row = row0 + g;
            float mu = gelu_f(p0[g] + bb30);
            float lv = gelu_f(p1[g] + bb31);
            mu_tab[row] = mu;
            lmda_tab[row] = expf(-fmaxf(lv, 1e-8f));
        }
    }
}

// ---------------------------------------------------------------------------
// Kernel 3: FUSED gather + backward scan + forward scan + K-reduction.
// One 64-thread block = 4 users x 16 skills. All per-chain state in LDS:
//   a_lds  [64][201]  51.5 KB  (alpha stream; pad 200->201: stride 201 words
//                               -> tid*9 mod 32 is a permutation -> 0-conflict)
//   l_lds/mu_lds [4][200] f32  (16-lane broadcast reads, 4 distinct banks)
//   mk_lds [4][200] u16
// Total 59.5 KB static LDS -> 2 blocks/CU.
// bwd stores the INCOMING alpha at index t (== alpha_next[t] of the
// reference, since bwd processes t+1 before t), so fwd reads ap[t] directly.
// beta of the reference bwd scan is dead code (never collected) -> omitted.
// mf.sum(-1) == popcount(mask) -> no second shuffle reduction.
// v_rcp_f32 instead of IEEE div: ~2.4e-7 rel/step, contractive recurrences,
// ~5e-5 accumulated vs 5.0e-3 threshold (9.8e-4 measured headroom in R1).
// ---------------------------------------------------------------------------
__global__ __launch_bounds__(64) void scan_fused_kernel(
    const int* __restrict__ q_id, const float* __restrict__ resp,
    const float* __restrict__ mu_tab, const float* __restrict__ lmda_tab,
    const uint32_t* __restrict__ mask_tab, float* __restrict__ out)
{
    __shared__ float a_lds[64][201];
    __shared__ float l_lds[4][T_DIM];
    __shared__ float mu_lds[4][T_DIM];
    __shared__ uint16_t mk_lds[4][T_DIM];
    int tid = threadIdx.x;
    int u0 = blockIdx.x * 4;

    // ---- gather: 800 (u_local, t) pairs, table lookups from L2/L3
    for (int idx = tid; idx < 4 * T_DIM; idx += 64) {
        int ul = idx / T_DIM, t = idx - ul * T_DIM;
        int g = (u0 + ul) * T_DIM + t;
        int q = q_id[g];
        float rv = resp[g];
        int ix = 2 * q + (rv != 0.0f ? 1 : 0);
        l_lds[ul][t]  = lmda_tab[ix];
        mu_lds[ul][t] = mu_tab[ix];
        mk_lds[ul][t] = (uint16_t)mask_tab[q];
    }
    __syncthreads();

    int ul = tid >> 4, k = tid & 15;
    float* ap = a_lds[tid];

    // ---- backward scan (t = T-1 .. 0), 1-deep LDS prefetch
    float alpha = 0.0f;
    float l_n = l_lds[ul][T_DIM - 1];
    uint32_t m_n = mk_lds[ul][T_DIM - 1];
    #pragma unroll 4
    for (int t = T_DIM - 1; t >= 0; --t) {
        float l = l_n;
        uint32_t m = m_n;
        if (t > 0) { l_n = l_lds[ul][t - 1]; m_n = mk_lds[ul][t - 1]; }
        ap[t] = alpha;   // incoming state == alpha_next[t]
        float an = (l + alpha) * __builtin_amdgcn_rcpf(1.0f + l + alpha);
        if ((m >> k) & 1) alpha = an;
    }
    // ap[] re-read only by the same thread; lgkmcnt ordering suffices.

    // ---- forward scan (t = 0 .. T-1) + 16-lane reduction
    float ability = 0.0f;
    float l2 = l_lds[ul][0], mu2 = mu_lds[ul][0];
    uint32_t m2 = mk_lds[ul][0];
    float a2 = ap[0];
    #pragma unroll 4
    for (int t = 0; t < T_DIM; ++t) {
        float l = l2, mu_ = mu2, a = a2;
        uint32_t m = m2;
        if (t < T_DIM - 1) {
            l2 = l_lds[ul][t + 1];
            mu2 = mu_lds[ul][t + 1];
            m2 = mk_lds[ul][t + 1];
            a2 = ap[t + 1];
        }
        // b_nxt = a_nxt in the reference => numerator term a^2; LMDA_THETA = 1
        float mt = (ability + mu_ * l + a * a) * __builtin_amdgcn_rcpf(1.0f + l + a);
        bool msk = (m >> k) & 1;
        ability = msk ? mt : ability;
        float s = msk ? ability : 0.0f;
        #pragma unroll
        for (int off = 1; off < 16; off <<= 1) s += __shfl_xor(s, off);
        if (k == 0) {
            float c = (float)__popc((unsigned)(m & 0xffffu));
            out[(u0 + ul) * T_DIM + t] = s * __builtin_amdgcn_rcpf(fmaxf(c, 1e-8f));
        }
    }
}

// ---------------------------------------------------------------------------
extern "C" void kernel_launch(void* const* d_in, const int* in_sizes, int n_in,
                              void* d_out, int out_size, void* d_ws, size_t ws_size,
                              hipStream_t stream) {
    // setup_inputs order: mask, q_id, kmap, resp, diff_mu, disc_mu, W1,b1,W2,b2,W3,b3
    // mask (d_in[0]) is UNUSED by the reference computation.
    const int*     q_id    = (const int*)d_in[1];
    const uint8_t* kmap    = (const uint8_t*)d_in[2];   // layout probed at runtime
    const float*   resp    = (const float*)d_in[3];
    const float*   diff_mu = (const float*)d_in[4];
    const float*   disc_mu = (const float*)d_in[5];
    const float*   W1      = (const float*)d_in[6];
    const float*   b1      = (const float*)d_in[7];
    const float*   W2      = (const float*)d_in[8];
    const float*   b2      = (const float*)d_in[9];
    const float*   W3      = (const float*)d_in[10];
    const float*   b3      = (const float*)d_in[11];
    float* out = (float*)d_out;

    // workspace layout (~80 KB now — alphas/streams all live in LDS)
    char* w = (char*)d_ws;
    float* mu_tab      = (float*)w;      w += (size_t)N_ROWS * 4;
    float* lmda_tab    = (float*)w;      w += (size_t)N_ROWS * 4;
    uint32_t* mask_tab = (uint32_t*)w;   w += (size_t)Q_DIM * 4;
    uint32_t* flag     = (uint32_t*)w;   w += 64;

    hipLaunchKernelGGL(probe_kernel, dim3(1), dim3(64), 0, stream,
                       (const uint32_t*)kmap, flag);
    hipLaunchKernelGGL(pack_kmap_kernel, dim3(Q_DIM / 256), dim3(256), 0, stream,
                       kmap, flag, mask_tab);
    hipLaunchKernelGGL(mlp_table_kernel, dim3(N_ROWS / 8), dim3(64), 0, stream,
                       diff_mu, disc_mu, W1, b1, W2, b2, W3, b3, mu_tab, lmda_tab);
    hipLaunchKernelGGL(scan_fused_kernel, dim3(U_DIM / 4), dim3(64), 0, stream,
                       q_id, resp, mu_tab, lmda_tab, mask_tab, out);
}

// Round 4
// 149.059 us; speedup vs baseline: 1.6150x; 1.1215x over previous
//
#include <hip/hip_runtime.h>
#include <hip/hip_bf16.h>
#include <stdint.h>

// Problem constants (fixed by reference file)
#define U_DIM 2048
#define T_DIM 200
#define Q_DIM 4096
#define K_DIM 16
#define H_DIM 256
#define N_UT  (U_DIM * T_DIM)   // 409600
#define N_ROWS (Q_DIM * 2)      // 8192 distinct (q, resp) MLP inputs
#define UK    (U_DIM * K_DIM)   // 32768 scan chains

typedef float f4 __attribute__((ext_vector_type(4)));

__device__ __forceinline__ float gelu_f(float x) {
    // exact gelu (approximate=False): 0.5*x*(1+erf(x/sqrt(2)))
    return 0.5f * x * (1.0f + erff(x * 0.70710678118654752440f));
}

// ---------------------------------------------------------------------------
// Kernel 0: probe kmap's storage layout (byte-bools vs int32-bools).
// ---------------------------------------------------------------------------
__global__ __launch_bounds__(64) void probe_kernel(const uint32_t* __restrict__ kmap_w,
                                                   uint32_t* __restrict__ flag) {
    int tid = threadIdx.x;
    uint32_t any = 0;
    #pragma unroll
    for (int i = 0; i < 16; ++i) any |= (kmap_w[tid + 64 * i] > 1u) ? 1u : 0u;
    uint64_t b = __ballot(any != 0);
    if (tid == 0) *flag = (b != 0) ? 1u : 0u;
}

// ---------------------------------------------------------------------------
// Kernel 1: pack kmap (Q,K) bool -> 16-bit mask, honoring probed layout
// ---------------------------------------------------------------------------
__global__ void pack_kmap_kernel(const uint8_t* __restrict__ kmap,
                                 const uint32_t* __restrict__ flag,
                                 uint32_t* __restrict__ mask_tab) {
    int q = blockIdx.x * blockDim.x + threadIdx.x;
    if (q >= Q_DIM) return;
    uint32_t m = 0;
    if (*flag) {
        const uint32_t* p = (const uint32_t*)(kmap + (size_t)q * K_DIM);
        #pragma unroll
        for (int w = 0; w < 4; ++w) {
            uint32_t v = p[w];
            #pragma unroll
            for (int b = 0; b < 4; ++b)
                m |= (((v >> (8 * b)) & 0xffu) ? 1u : 0u) << (4 * w + b);
        }
    } else {
        const int* ki = (const int*)kmap + (size_t)q * K_DIM;
        #pragma unroll
        for (int k = 0; k < K_DIM; ++k)
            m |= (ki[k] ? 1u : 0u) << k;
    }
    mask_tab[q] = m;
}

// ---------------------------------------------------------------------------
// Kernel 2: fp32 MLP over 8192 rows. 128 threads/block, G=8 rows/block:
// wave0 = rows 0..3, wave1 = rows 4..7. Both waves stream the same W2
// addresses (L1/L2 dedup); 2048 waves total = 2 waves/SIMD so the co-wave
// hides W2 load latency (R2: 1024 waves = 1/SIMD, every L2 miss exposed).
// ---------------------------------------------------------------------------
__global__ __launch_bounds__(128) void mlp_table_kernel(
    const float* __restrict__ diff_mu, const float* __restrict__ disc_mu,
    const float* __restrict__ W1, const float* __restrict__ b1,
    const float* __restrict__ W2, const float* __restrict__ b2,
    const float* __restrict__ W3, const float* __restrict__ b3,
    float* __restrict__ mu_tab, float* __restrict__ lmda_tab)
{
    __shared__ float h1t[H_DIM][12];  // [col i][row g], pad 8->12 (16B-aligned rows)
    int tid  = threadIdx.x;
    int lane = tid & 63;
    int wv_id = tid >> 6;             // wave 0/1
    int row0 = blockIdx.x * 8;

    // ---- layer 1: this wave's 4 rows x this lane's 4 cols
    f4 w1a = *(const f4*)&W1[0 * H_DIM + 4 * lane];
    f4 w1b = *(const f4*)&W1[1 * H_DIM + 4 * lane];
    f4 w1c = *(const f4*)&W1[2 * H_DIM + 4 * lane];
    f4 bb1 = *(const f4*)&b1[4 * lane];
    #pragma unroll
    for (int g = 0; g < 4; ++g) {
        int row = row0 + 4 * wv_id + g;
        int q = row >> 1;
        float rr = (float)(row & 1);
        float td = diff_mu[q];
        float ts = disc_mu[q];
        #pragma unroll
        for (int c = 0; c < 4; ++c) {
            float x = td * w1a[c] + ts * w1b[c] + rr * w1c[c] + bb1[c];
            h1t[4 * lane + c][4 * wv_id + g] = gelu_f(x);
        }
    }
    __syncthreads();

    // ---- layer 2: acc[g][c] = b2 + sum_i h1[g][i] * W2[i][4lane+c]
    float acc[4][4];
    f4 bb2 = *(const f4*)&b2[4 * lane];
    #pragma unroll
    for (int g = 0; g < 4; ++g) {
        acc[g][0] = bb2[0]; acc[g][1] = bb2[1]; acc[g][2] = bb2[2]; acc[g][3] = bb2[3];
    }
    #pragma unroll 8
    for (int i = 0; i < H_DIM; ++i) {
        f4 wv = *(const f4*)&W2[i * H_DIM + 4 * lane];
        f4 hh = *(const f4*)&h1t[i][4 * wv_id];   // uniform addr -> LDS broadcast
        #pragma unroll
        for (int c = 0; c < 4; ++c) {
            acc[0][c] += hh[0] * wv[c];
            acc[1][c] += hh[1] * wv[c];
            acc[2][c] += hh[2] * wv[c];
            acc[3][c] += hh[3] * wv[c];
        }
    }

    // ---- layer 3: thread's 4 j's are W3 elements 8lane..8lane+7
    f4 w3lo = *(const f4*)&W3[8 * lane];
    f4 w3hi = *(const f4*)&W3[8 * lane + 4];
    float p0[4], p1[4];
    #pragma unroll
    for (int g = 0; g < 4; ++g) {
        float h0 = gelu_f(acc[g][0]);
        float h1v = gelu_f(acc[g][1]);
        float h2v = gelu_f(acc[g][2]);
        float h3v = gelu_f(acc[g][3]);
        p0[g] = h0 * w3lo[0] + h1v * w3lo[2] + h2v * w3hi[0] + h3v * w3hi[2];
        p1[g] = h0 * w3lo[1] + h1v * w3lo[3] + h2v * w3hi[1] + h3v * w3hi[3];
    }
    #pragma unroll
    for (int g = 0; g < 4; ++g) {
        #pragma unroll
        for (int off = 1; off < 64; off <<= 1) {
            p0[g] += __shfl_xor(p0[g], off);
            p1[g] += __shfl_xor(p1[g], off);
        }
    }
    if (lane == 0) {
        float bb30 = b3[0], bb31 = b3[1];
        #pragma unroll
        for (int g = 0; g < 4; ++g) {
            int row = row0 + 4 * wv_id + g;
            float mu = gelu_f(p0[g] + bb30);
            float lv = gelu_f(p1[g] + bb31);
            mu_tab[row] = mu;
            lmda_tab[row] = expf(-fmaxf(lv, 1e-8f));
        }
    }
}

// ---------------------------------------------------------------------------
// Kernel 3: FUSED gather + bwd scan + fwd scan + K-reduction.
// R3 changes vs R2:
//  (a) gather batches all q/resp loads into registers before issuing the
//      dependent table lookups (1-2 exposed miss latencies instead of 13);
//  (b) the 16-lane shuffle reduction is HOISTED out of the fwd t-loop:
//      fwd stores (msk ? ability : 0) into the dead alpha slot ap[t], and a
//      post-barrier phase reduces 16 LDS values per (u,t) with all lanes
//      parallel over outputs. Fwd iter = ~20-cyc ability chain + 1 ds_write.
// ---------------------------------------------------------------------------
__global__ __launch_bounds__(64) void scan_fused_kernel(
    const int* __restrict__ q_id, const float* __restrict__ resp,
    const float* __restrict__ mu_tab, const float* __restrict__ lmda_tab,
    const uint32_t* __restrict__ mask_tab, float* __restrict__ out)
{
    __shared__ float a_lds[64][201];   // stride 201: tid*9 mod 32 permutes -> 0-conflict
    __shared__ float l_lds[4][T_DIM];
    __shared__ float mu_lds[4][T_DIM];
    __shared__ uint16_t mk_lds[4][T_DIM];
    int tid = threadIdx.x;
    int u0 = blockIdx.x * 4;

    // ---- gather (batched): 800 (ul,t) pairs
    int   qv[13];
    float rv[13];
    #pragma unroll
    for (int p = 0; p < 13; ++p) {
        int idx = tid + 64 * p;
        if (idx < 4 * T_DIM) {
            int ul = idx / T_DIM, t = idx - ul * T_DIM;
            int g = (u0 + ul) * T_DIM + t;
            qv[p] = q_id[g];
            rv[p] = resp[g];
        }
    }
    #pragma unroll
    for (int p = 0; p < 13; ++p) {
        int idx = tid + 64 * p;
        if (idx < 4 * T_DIM) {
            int ul = idx / T_DIM, t = idx - ul * T_DIM;
            int ix = 2 * qv[p] + (rv[p] != 0.0f ? 1 : 0);
            l_lds[ul][t]  = lmda_tab[ix];
            mu_lds[ul][t] = mu_tab[ix];
            mk_lds[ul][t] = (uint16_t)mask_tab[qv[p]];
        }
    }
    __syncthreads();

    int ul = tid >> 4, k = tid & 15;
    float* ap = a_lds[tid];

    // ---- backward scan (t = T-1 .. 0), 1-deep LDS prefetch
    float alpha = 0.0f;
    float l_n = l_lds[ul][T_DIM - 1];
    uint32_t m_n = mk_lds[ul][T_DIM - 1];
    #pragma unroll 4
    for (int t = T_DIM - 1; t >= 0; --t) {
        float l = l_n;
        uint32_t m = m_n;
        if (t > 0) { l_n = l_lds[ul][t - 1]; m_n = mk_lds[ul][t - 1]; }
        ap[t] = alpha;   // incoming state == alpha_next[t]
        float an = (l + alpha) * __builtin_amdgcn_rcpf(1.0f + l + alpha);
        if ((m >> k) & 1) alpha = an;
    }

    // ---- forward scan (t = 0 .. T-1); store masked ability over ap[t]
    float ability = 0.0f;
    float l2 = l_lds[ul][0], mu2 = mu_lds[ul][0];
    uint32_t m2 = mk_lds[ul][0];
    float a2 = ap[0];
    #pragma unroll 4
    for (int t = 0; t < T_DIM; ++t) {
        float l = l2, mu_ = mu2, a = a2;
        uint32_t m = m2;
        if (t < T_DIM - 1) {
            l2 = l_lds[ul][t + 1];
            mu2 = mu_lds[ul][t + 1];
            m2 = mk_lds[ul][t + 1];
            a2 = ap[t + 1];          // read t+1 BEFORE overwriting t (same thread)
        }
        // b_nxt = a_nxt => numerator a^2; LMDA_THETA = 1
        float mt = (ability + mu_ * l + a * a) * __builtin_amdgcn_rcpf(1.0f + l + a);
        bool msk = (m >> k) & 1;
        ability = msk ? mt : ability;
        ap[t] = msk ? ability : 0.0f;
    }
    __syncthreads();

    // ---- K-reduction, all lanes parallel over the 800 outputs
    #pragma unroll
    for (int p = 0; p < 13; ++p) {
        int idx = tid + 64 * p;
        if (idx < 4 * T_DIM) {
            int uo = idx / T_DIM, t = idx - uo * T_DIM;
            float s = 0.0f;
            #pragma unroll
            for (int kk = 0; kk < 16; ++kk) s += a_lds[uo * 16 + kk][t];
            float c = (float)__popc((unsigned)(mk_lds[uo][t] & 0xffffu));
            out[(u0 + uo) * T_DIM + t] = s * __builtin_amdgcn_rcpf(fmaxf(c, 1e-8f));
        }
    }
}

// ---------------------------------------------------------------------------
extern "C" void kernel_launch(void* const* d_in, const int* in_sizes, int n_in,
                              void* d_out, int out_size, void* d_ws, size_t ws_size,
                              hipStream_t stream) {
    // setup_inputs order: mask, q_id, kmap, resp, diff_mu, disc_mu, W1,b1,W2,b2,W3,b3
    // mask (d_in[0]) is UNUSED by the reference computation.
    const int*     q_id    = (const int*)d_in[1];
    const uint8_t* kmap    = (const uint8_t*)d_in[2];   // layout probed at runtime
    const float*   resp    = (const float*)d_in[3];
    const float*   diff_mu = (const float*)d_in[4];
    const float*   disc_mu = (const float*)d_in[5];
    const float*   W1      = (const float*)d_in[6];
    const float*   b1      = (const float*)d_in[7];
    const float*   W2      = (const float*)d_in[8];
    const float*   b2      = (const float*)d_in[9];
    const float*   W3      = (const float*)d_in[10];
    const float*   b3      = (const float*)d_in[11];
    float* out = (float*)d_out;

    char* w = (char*)d_ws;
    float* mu_tab      = (float*)w;      w += (size_t)N_ROWS * 4;
    float* lmda_tab    = (float*)w;      w += (size_t)N_ROWS * 4;
    uint32_t* mask_tab = (uint32_t*)w;   w += (size_t)Q_DIM * 4;
    uint32_t* flag     = (uint32_t*)w;   w += 64;

    hipLaunchKernelGGL(probe_kernel, dim3(1), dim3(64), 0, stream,
                       (const uint32_t*)kmap, flag);
    hipLaunchKernelGGL(pack_kmap_kernel, dim3(Q_DIM / 256), dim3(256), 0, stream,
                       kmap, flag, mask_tab);
    hipLaunchKernelGGL(mlp_table_kernel, dim3(N_ROWS / 8), dim3(128), 0, stream,
                       diff_mu, disc_mu, W1, b1, W2, b2, W3, b3, mu_tab, lmda_tab);
    hipLaunchKernelGGL(scan_fused_kernel, dim3(U_DIM / 4), dim3(64), 0, stream,
                       q_id, resp, mu_tab, lmda_tab, mask_tab, out);
}

// Round 5
// 121.896 us; speedup vs baseline: 1.9749x; 1.2228x over previous
//
#include <hip/hip_runtime.h>
#include <hip/hip_bf16.h>
#include <stdint.h>

// Problem constants (fixed by reference file)
#define U_DIM 2048
#define T_DIM 200
#define Q_DIM 4096
#define K_DIM 16
#define H_DIM 256
#define N_ROWS (Q_DIM * 2)      // 8192 distinct (q, resp) MLP inputs

typedef float f4 __attribute__((ext_vector_type(4)));
typedef float f2 __attribute__((ext_vector_type(2)));

__device__ __forceinline__ float gelu_f(float x) {
    // exact gelu (approximate=False): 0.5*x*(1+erf(x/sqrt(2)))
    return 0.5f * x * (1.0f + erff(x * 0.70710678118654752440f));
}

// ---------------------------------------------------------------------------
// Kernel 1: probe kmap layout + pack to 16-bit masks (fused).
// Each block independently derives the bool-storage flag from kmap's first
// 4 KB (byte-bools: some uint32 word > 1 with certainty since
// P(word<=1)=0.75^3/word over 1024 words; int32-bools: all words 0/1).
// No cross-block communication -> dispatch-order safe (G16).
// ---------------------------------------------------------------------------
__global__ __launch_bounds__(256) void pack_kmap_kernel(
    const uint8_t* __restrict__ kmap, uint32_t* __restrict__ mask_tab)
{
    __shared__ uint32_t sflag;
    int tid = threadIdx.x;
    if (tid < 64) {   // wave 0 only
        const uint32_t* kw = (const uint32_t*)kmap;
        uint32_t any = 0;
        #pragma unroll
        for (int i = 0; i < 16; ++i) any |= (kw[tid + 64 * i] > 1u) ? 1u : 0u;
        uint64_t b = __ballot(any != 0);
        if (tid == 0) sflag = (b != 0) ? 1u : 0u;
    }
    __syncthreads();
    int q = blockIdx.x * 256 + tid;
    uint32_t m = 0;
    if (sflag) {   // 1 byte per element
        const uint32_t* p = (const uint32_t*)(kmap + (size_t)q * K_DIM);
        #pragma unroll
        for (int w = 0; w < 4; ++w) {
            uint32_t v = p[w];
            #pragma unroll
            for (int b = 0; b < 4; ++b)
                m |= (((v >> (8 * b)) & 0xffu) ? 1u : 0u) << (4 * w + b);
        }
    } else {       // int32 per element
        const int* ki = (const int*)kmap + (size_t)q * K_DIM;
        #pragma unroll
        for (int k = 0; k < K_DIM; ++k)
            m |= (ki[k] ? 1u : 0u) << k;
    }
    mask_tab[q] = m;
}

// ---------------------------------------------------------------------------
// Kernel 2: fp32 MLP over 8192 rows -> mu_tab, lmda_tab.
// R4 restructure: 256 threads (4 waves), G=8 rows/block, layer-2 K-SPLIT:
// wave w owns k in [64w, 64w+64) -> 64 W2 loads/wave (4x fewer than R3),
// 1024 blocks x 4 waves = 4 waves/SIMD (2x R3's TLP). Partial accumulators
// reduced through 32 KB LDS; layers 1/3 as before.
// ---------------------------------------------------------------------------
__global__ __launch_bounds__(256) void mlp_table_kernel(
    const float* __restrict__ diff_mu, const float* __restrict__ disc_mu,
    const float* __restrict__ W1, const float* __restrict__ b1,
    const float* __restrict__ W2, const float* __restrict__ b2,
    const float* __restrict__ W3, const float* __restrict__ b3,
    float* __restrict__ mu_tab, float* __restrict__ lmda_tab)
{
    __shared__ float h1t[H_DIM][8];        // 8 KB: [col i][row g]
    __shared__ float red[4][8][H_DIM];     // 32 KB: [wave][row g][col j]
    int tid  = threadIdx.x;
    int lane = tid & 63;
    int w    = tid >> 6;                   // wave 0..3
    int row0 = blockIdx.x * 8;

    // ---- layer 1: lane handles input-col i = 64w+lane for all 8 rows
    {
        int i = 64 * w + lane;
        float w1a = W1[0 * H_DIM + i], w1b = W1[1 * H_DIM + i],
              w1c = W1[2 * H_DIM + i], bi = b1[i];
        float hv[8];
        #pragma unroll
        for (int g = 0; g < 8; ++g) {
            int row = row0 + g;
            float td = diff_mu[row >> 1];
            float ts = disc_mu[row >> 1];
            float rr = (float)(row & 1);
            hv[g] = gelu_f(td * w1a + ts * w1b + rr * w1c + bi);
        }
        *(f4*)&h1t[i][0] = (f4){hv[0], hv[1], hv[2], hv[3]};
        *(f4*)&h1t[i][4] = (f4){hv[4], hv[5], hv[6], hv[7]};
    }
    __syncthreads();

    // ---- layer 2 partial: k in [64w, 64w+64), cols 4*lane..+3, all 8 rows
    float acc[8][4];
    #pragma unroll
    for (int g = 0; g < 8; ++g) { acc[g][0] = acc[g][1] = acc[g][2] = acc[g][3] = 0.0f; }
    #pragma unroll 4
    for (int s = 0; s < 64; ++s) {
        int i = 64 * w + s;
        f4 wv = *(const f4*)&W2[i * H_DIM + 4 * lane];
        f4 hA = *(const f4*)&h1t[i][0];    // wave-uniform addr -> broadcast
        f4 hB = *(const f4*)&h1t[i][4];
        #pragma unroll
        for (int c = 0; c < 4; ++c) {
            acc[0][c] += hA[0] * wv[c];
            acc[1][c] += hA[1] * wv[c];
            acc[2][c] += hA[2] * wv[c];
            acc[3][c] += hA[3] * wv[c];
            acc[4][c] += hB[0] * wv[c];
            acc[5][c] += hB[1] * wv[c];
            acc[6][c] += hB[2] * wv[c];
            acc[7][c] += hB[3] * wv[c];
        }
    }
    #pragma unroll
    for (int g = 0; g < 8; ++g)
        *(f4*)&red[w][g][4 * lane] = (f4){acc[g][0], acc[g][1], acc[g][2], acc[g][3]};
    __syncthreads();

    // ---- cross-wave reduce + layer 3 (waves 0,1 only; rows 4*w2..4*w2+3)
    if (tid < 128) {
        int w2 = tid >> 6;
        int l  = tid & 63;
        f4 bb2  = *(const f4*)&b2[4 * l];
        f4 w3lo = *(const f4*)&W3[8 * l];        // (j0,c0)(j0,c1)(j1,c0)(j1,c1)
        f4 w3hi = *(const f4*)&W3[8 * l + 4];
        float p0[4], p1[4];
        #pragma unroll
        for (int gg = 0; gg < 4; ++gg) {
            int g = 4 * w2 + gg;
            f4 s = bb2;
            #pragma unroll
            for (int ww = 0; ww < 4; ++ww) {
                f4 r = *(const f4*)&red[ww][g][4 * l];
                s[0] += r[0]; s[1] += r[1]; s[2] += r[2]; s[3] += r[3];
            }
            float h0 = gelu_f(s[0]), h1v = gelu_f(s[1]),
                  h2v = gelu_f(s[2]), h3v = gelu_f(s[3]);
            p0[gg] = h0 * w3lo[0] + h1v * w3lo[2] + h2v * w3hi[0] + h3v * w3hi[2];
            p1[gg] = h0 * w3lo[1] + h1v * w3lo[3] + h2v * w3hi[1] + h3v * w3hi[3];
        }
        #pragma unroll
        for (int gg = 0; gg < 4; ++gg) {
            #pragma unroll
            for (int off = 1; off < 64; off <<= 1) {
                p0[gg] += __shfl_xor(p0[gg], off);
                p1[gg] += __shfl_xor(p1[gg], off);
            }
        }
        if (l == 0) {
            float bb30 = b3[0], bb31 = b3[1];
            #pragma unroll
            for (int gg = 0; gg < 4; ++gg) {
                int row = row0 + 4 * w2 + gg;
                float mu = gelu_f(p0[gg] + bb30);
                float lv = gelu_f(p1[gg] + bb31);
                mu_tab[row]   = mu;
                lmda_tab[row] = expf(-fmaxf(lv, 1e-8f));
            }
        }
    }
}

// ---------------------------------------------------------------------------
// Kernel 3: FUSED gather + bwd scan + fwd scan + K-reduction.
// R4 changes vs R3 (attacking the ~120-cyc exposed LDS latency at 1.6 wv/CU):
//  (a) gather pre-stores L1 = 1+lmda and A = mu*lmda as a packed float2
//      (one ds_read_b64 in fwd instead of two b32);
//  (b) bwd chain: alpha' = 1 - rcp(L1+alpha)  (~24-cyc carried chain;
//      rcp error is 1-ulp absolute ~2.4e-7, harmless at 5e-3 threshold);
//  (c) fwd chain: den/rcp/c1 = A + a^2 are ability-independent -> off the
//      carried chain; chain = add+mul+cndmask (~12 cyc);
//  (d) 4-deep explicit prefetch pipeline (named slot registers, compile-time
//      indices only) so prefetch distance ~4x30 cyc > 120-cyc LDS latency.
// ---------------------------------------------------------------------------
__global__ __launch_bounds__(64) void scan_fused_kernel(
    const int* __restrict__ q_id, const float* __restrict__ resp,
    const float* __restrict__ mu_tab, const float* __restrict__ lmda_tab,
    const uint32_t* __restrict__ mask_tab, float* __restrict__ out)
{
    __shared__ float a_lds[64][201];       // stride 201 -> conflict-free
    __shared__ f2 la_lds[4][T_DIM];        // (L1, A)
    __shared__ uint16_t mk_lds[4][T_DIM];
    int tid = threadIdx.x;
    int u0 = blockIdx.x * 4;

    // ---- gather (batched): 800 (ul,t) pairs
    int   qv[13];
    float rv[13];
    #pragma unroll
    for (int p = 0; p < 13; ++p) {
        int idx = tid + 64 * p;
        if (idx < 4 * T_DIM) {
            int ul = idx / T_DIM, t = idx - ul * T_DIM;
            int g = (u0 + ul) * T_DIM + t;
            qv[p] = q_id[g];
            rv[p] = resp[g];
        }
    }
    #pragma unroll
    for (int p = 0; p < 13; ++p) {
        int idx = tid + 64 * p;
        if (idx < 4 * T_DIM) {
            int ul = idx / T_DIM, t = idx - ul * T_DIM;
            int ix = 2 * qv[p] + (rv[p] != 0.0f ? 1 : 0);
            float l  = lmda_tab[ix];
            float mu = mu_tab[ix];
            la_lds[ul][t] = (f2){1.0f + l, mu * l};
            mk_lds[ul][t] = (uint16_t)mask_tab[qv[p]];
        }
    }
    __syncthreads();

    int ul = tid >> 4, k = tid & 15;
    float* ap = a_lds[tid];
    const f2* la = la_lds[ul];
    const uint16_t* mk = mk_lds[ul];

    // ---- backward scan, t = 199..0, 4-deep pipeline (slot j <-> t = tb+j)
    float alpha = 0.0f;
    float L1s0 = la[196][0], L1s1 = la[197][0], L1s2 = la[198][0], L1s3 = la[199][0];
    uint32_t ms0 = mk[196], ms1 = mk[197], ms2 = mk[198], ms3 = mk[199];
    for (int tb = 196; tb >= 0; tb -= 4) {
        int p3 = (tb >= 1) ? tb - 1 : 0;
        int p2 = (tb >= 2) ? tb - 2 : 0;
        int p1 = (tb >= 3) ? tb - 3 : 0;
        int p0 = (tb >= 4) ? tb - 4 : 0;
        { float L1 = L1s3; uint32_t m = ms3; L1s3 = la[p3][0]; ms3 = mk[p3];
          ap[tb + 3] = alpha;
          float an = 1.0f - __builtin_amdgcn_rcpf(L1 + alpha);
          alpha = ((m >> k) & 1) ? an : alpha; }
        { float L1 = L1s2; uint32_t m = ms2; L1s2 = la[p2][0]; ms2 = mk[p2];
          ap[tb + 2] = alpha;
          float an = 1.0f - __builtin_amdgcn_rcpf(L1 + alpha);
          alpha = ((m >> k) & 1) ? an : alpha; }
        { float L1 = L1s1; uint32_t m = ms1; L1s1 = la[p1][0]; ms1 = mk[p1];
          ap[tb + 1] = alpha;
          float an = 1.0f - __builtin_amdgcn_rcpf(L1 + alpha);
          alpha = ((m >> k) & 1) ? an : alpha; }
        { float L1 = L1s0; uint32_t m = ms0; L1s0 = la[p0][0]; ms0 = mk[p0];
          ap[tb + 0] = alpha;
          float an = 1.0f - __builtin_amdgcn_rcpf(L1 + alpha);
          alpha = ((m >> k) & 1) ? an : alpha; }
    }

    // ---- forward scan, t = 0..199, 4-deep pipeline; overwrite ap[t] with
    //      masked ability for the reduction phase. (fwd writes t<=tb+3 while
    //      prefetch reads t>=tb+4: bwd values still intact -> no hazard.)
    float ability = 0.0f;
    f2 lv0 = la[0], lv1 = la[1], lv2 = la[2], lv3 = la[3];
    uint32_t n0 = mk[0], n1 = mk[1], n2 = mk[2], n3 = mk[3];
    float av0 = ap[0], av1 = ap[1], av2 = ap[2], av3 = ap[3];
    for (int tb = 0; tb < 200; tb += 4) {
        int p0 = (tb + 4 < 200) ? tb + 4 : 199;
        int p1 = (tb + 5 < 200) ? tb + 5 : 199;
        int p2 = (tb + 6 < 200) ? tb + 6 : 199;
        int p3 = (tb + 7 < 200) ? tb + 7 : 199;
        { f2 v = lv0; uint32_t m = n0; float a = av0;
          lv0 = la[p0]; n0 = mk[p0]; av0 = ap[p0];
          float r = __builtin_amdgcn_rcpf(v[0] + a);
          float c1 = v[1] + a * a;
          float mt = (ability + c1) * r;
          bool msk = (m >> k) & 1;
          ability = msk ? mt : ability;
          ap[tb + 0] = msk ? ability : 0.0f; }
        { f2 v = lv1; uint32_t m = n1; float a = av1;
          lv1 = la[p1]; n1 = mk[p1]; av1 = ap[p1];
          float r = __builtin_amdgcn_rcpf(v[0] + a);
          float c1 = v[1] + a * a;
          float mt = (ability + c1) * r;
          bool msk = (m >> k) & 1;
          ability = msk ? mt : ability;
          ap[tb + 1] = msk ? ability : 0.0f; }
        { f2 v = lv2; uint32_t m = n2; float a = av2;
          lv2 = la[p2]; n2 = mk[p2]; av2 = ap[p2];
          float r = __builtin_amdgcn_rcpf(v[0] + a);
          float c1 = v[1] + a * a;
          float mt = (ability + c1) * r;
          bool msk = (m >> k) & 1;
          ability = msk ? mt : ability;
          ap[tb + 2] = msk ? ability : 0.0f; }
        { f2 v = lv3; uint32_t m = n3; float a = av3;
          lv3 = la[p3]; n3 = mk[p3]; av3 = ap[p3];
          float r = __builtin_amdgcn_rcpf(v[0] + a);
          float c1 = v[1] + a * a;
          float mt = (ability + c1) * r;
          bool msk = (m >> k) & 1;
          ability = msk ? mt : ability;
          ap[tb + 3] = msk ? ability : 0.0f; }
    }
    __syncthreads();

    // ---- K-reduction, all lanes parallel over the 800 outputs
    #pragma unroll
    for (int p = 0; p < 13; ++p) {
        int idx = tid + 64 * p;
        if (idx < 4 * T_DIM) {
            int uo = idx / T_DIM, t = idx - uo * T_DIM;
            float s = 0.0f;
            #pragma unroll
            for (int kk = 0; kk < 16; ++kk) s += a_lds[uo * 16 + kk][t];
            float c = (float)__popc((unsigned)(mk_lds[uo][t] & 0xffffu));
            out[(u0 + uo) * T_DIM + t] = s * __builtin_amdgcn_rcpf(fmaxf(c, 1e-8f));
        }
    }
}

// ---------------------------------------------------------------------------
extern "C" void kernel_launch(void* const* d_in, const int* in_sizes, int n_in,
                              void* d_out, int out_size, void* d_ws, size_t ws_size,
                              hipStream_t stream) {
    // setup_inputs order: mask, q_id, kmap, resp, diff_mu, disc_mu, W1,b1,W2,b2,W3,b3
    // mask (d_in[0]) is UNUSED by the reference computation.
    const int*     q_id    = (const int*)d_in[1];
    const uint8_t* kmap    = (const uint8_t*)d_in[2];   // layout probed per-block
    const float*   resp    = (const float*)d_in[3];
    const float*   diff_mu = (const float*)d_in[4];
    const float*   disc_mu = (const float*)d_in[5];
    const float*   W1      = (const float*)d_in[6];
    const float*   b1      = (const float*)d_in[7];
    const float*   W2      = (const float*)d_in[8];
    const float*   b2      = (const float*)d_in[9];
    const float*   W3      = (const float*)d_in[10];
    const float*   b3      = (const float*)d_in[11];
    float* out = (float*)d_out;

    char* w = (char*)d_ws;
    float* mu_tab      = (float*)w;      w += (size_t)N_ROWS * 4;
    float* lmda_tab    = (float*)w;      w += (size_t)N_ROWS * 4;
    uint32_t* mask_tab = (uint32_t*)w;   w += (size_t)Q_DIM * 4;

    hipLaunchKernelGGL(pack_kmap_kernel, dim3(Q_DIM / 256), dim3(256), 0, stream,
                       kmap, mask_tab);
    hipLaunchKernelGGL(mlp_table_kernel, dim3(N_ROWS / 8), dim3(256), 0, stream,
                       diff_mu, disc_mu, W1, b1, W2, b2, W3, b3, mu_tab, lmda_tab);
    hipLaunchKernelGGL(scan_fused_kernel, dim3(U_DIM / 4), dim3(64), 0, stream,
                       q_id, resp, mu_tab, lmda_tab, mask_tab, out);
}

// Round 7
// 119.659 us; speedup vs baseline: 2.0118x; 1.0187x over previous
//
#include <hip/hip_runtime.h>
#include <hip/hip_bf16.h>
#include <stdint.h>

// Problem constants (fixed by reference file)
#define U_DIM 2048
#define T_DIM 200
#define Q_DIM 4096
#define K_DIM 16
#define H_DIM 256
#define N_ROWS (Q_DIM * 2)      // 8192 distinct (q, resp) MLP inputs

typedef float f4 __attribute__((ext_vector_type(4)));
typedef float f2 __attribute__((ext_vector_type(2)));

__device__ __forceinline__ float gelu_f(float x) {
    // exact gelu (approximate=False): 0.5*x*(1+erf(x/sqrt(2)))
    return 0.5f * x * (1.0f + erff(x * 0.70710678118654752440f));
}

// ---------------------------------------------------------------------------
// Kernel 1: fp32 MLP over 8192 rows -> mu_tab, lmda_tab  (+ folded kmap pack)
// R5 restructure vs R4:
//  - G=16 rows/block, 512 blocks: W2 L2 traffic halves (268 -> 134 MB).
//  - acc[16][4] accumulated in one pass over W2; partials reduced through
//    a 32 KB red buffer in TWO 8-row phases (52 KB LDS total), with all
//    4 waves active in every phase (R4 idled half the block).
//  - kmap pack (+ its per-block layout probe) folded into blocks 0..15:
//    one launch fewer, no cross-block assumptions (G16-safe).
// ---------------------------------------------------------------------------
__global__ __launch_bounds__(256) void mlp_pack_kernel(
    const uint8_t* __restrict__ kmap, uint32_t* __restrict__ mask_tab,
    const float* __restrict__ diff_mu, const float* __restrict__ disc_mu,
    const float* __restrict__ W1, const float* __restrict__ b1,
    const float* __restrict__ W2, const float* __restrict__ b2,
    const float* __restrict__ W3, const float* __restrict__ b3,
    float* __restrict__ mu_tab, float* __restrict__ lmda_tab)
{
    __shared__ float h1t[H_DIM][20];      // 20 KB: [col i][row g], 16B-aligned rows
    __shared__ float red8[4][8][H_DIM];   // 32 KB: [wave][row g][col j]
    __shared__ uint32_t sflag;
    int tid  = threadIdx.x;
    int bid  = blockIdx.x;
    int row0 = bid * 16;

    // ---- folded kmap pack (blocks 0..15 cover all 4096 q's)
    if (bid < 16) {
        if (tid < 64) {   // probe bool storage: byte-bools vs int32-bools
            const uint32_t* kw = (const uint32_t*)kmap;
            uint32_t any = 0;
            #pragma unroll
            for (int i = 0; i < 16; ++i) any |= (kw[tid + 64 * i] > 1u) ? 1u : 0u;
            uint64_t b = __ballot(any != 0);
            if (tid == 0) sflag = (b != 0) ? 1u : 0u;
        }
        __syncthreads();
        int q = bid * 256 + tid;
        uint32_t m = 0;
        if (sflag) {   // 1 byte per element
            const uint32_t* p = (const uint32_t*)(kmap + (size_t)q * K_DIM);
            #pragma unroll
            for (int w = 0; w < 4; ++w) {
                uint32_t v = p[w];
                #pragma unroll
                for (int b = 0; b < 4; ++b)
                    m |= (((v >> (8 * b)) & 0xffu) ? 1u : 0u) << (4 * w + b);
            }
        } else {       // int32 per element
            const int* ki = (const int*)kmap + (size_t)q * K_DIM;
            #pragma unroll
            for (int k = 0; k < K_DIM; ++k)
                m |= (ki[k] ? 1u : 0u) << k;
        }
        mask_tab[q] = m;
    }

    // ---- layer 1: thread owns col i = tid for all 16 rows
    {
        int i = tid;
        float w1a = W1[i], w1b = W1[H_DIM + i], w1c = W1[2 * H_DIM + i], bi = b1[i];
        float hv[16];
        #pragma unroll
        for (int g = 0; g < 16; ++g) {
            int row = row0 + g;
            float td = diff_mu[row >> 1];
            float ts = disc_mu[row >> 1];
            float rr = (float)(row & 1);
            hv[g] = gelu_f(td * w1a + ts * w1b + rr * w1c + bi);
        }
        *(f4*)&h1t[i][0]  = (f4){hv[0],  hv[1],  hv[2],  hv[3]};
        *(f4*)&h1t[i][4]  = (f4){hv[4],  hv[5],  hv[6],  hv[7]};
        *(f4*)&h1t[i][8]  = (f4){hv[8],  hv[9],  hv[10], hv[11]};
        *(f4*)&h1t[i][12] = (f4){hv[12], hv[13], hv[14], hv[15]};
    }
    __syncthreads();

    // ---- layer 2: wave w owns k in [64w,64w+64); lane l owns cols 4l..4l+3
    int w = tid >> 6, l = tid & 63;
    float acc[16][4];
    #pragma unroll
    for (int g = 0; g < 16; ++g)
        acc[g][0] = acc[g][1] = acc[g][2] = acc[g][3] = 0.0f;
    #pragma unroll 4
    for (int s = 0; s < 64; ++s) {
        int i2 = 64 * w + s;
        f4 wv = *(const f4*)&W2[i2 * H_DIM + 4 * l];
        f4 hA = *(const f4*)&h1t[i2][0];    // wave-uniform addr -> broadcast
        f4 hB = *(const f4*)&h1t[i2][4];
        f4 hC = *(const f4*)&h1t[i2][8];
        f4 hD = *(const f4*)&h1t[i2][12];
        #pragma unroll
        for (int c = 0; c < 4; ++c) {
            acc[0][c]  += hA[0] * wv[c];
            acc[1][c]  += hA[1] * wv[c];
            acc[2][c]  += hA[2] * wv[c];
            acc[3][c]  += hA[3] * wv[c];
            acc[4][c]  += hB[0] * wv[c];
            acc[5][c]  += hB[1] * wv[c];
            acc[6][c]  += hB[2] * wv[c];
            acc[7][c]  += hB[3] * wv[c];
            acc[8][c]  += hC[0] * wv[c];
            acc[9][c]  += hC[1] * wv[c];
            acc[10][c] += hC[2] * wv[c];
            acc[11][c] += hC[3] * wv[c];
            acc[12][c] += hD[0] * wv[c];
            acc[13][c] += hD[1] * wv[c];
            acc[14][c] += hD[2] * wv[c];
            acc[15][c] += hD[3] * wv[c];
        }
    }

    // ---- two 8-row reduce + layer-3 phases; every wave handles 2 rows/phase
    f4 bb2  = *(const f4*)&b2[4 * l];
    f4 w3lo = *(const f4*)&W3[8 * l];        // (j0,c0)(j0,c1)(j1,c0)(j1,c1)
    f4 w3hi = *(const f4*)&W3[8 * l + 4];
    float bb30 = b3[0], bb31 = b3[1];
    #pragma unroll
    for (int phase = 0; phase < 2; ++phase) {
        int base = 8 * phase;
        __syncthreads();   // red8 free (phase 0: after L1 sync; phase 1: after reduce reads)
        #pragma unroll
        for (int g = 0; g < 8; ++g)
            *(f4*)&red8[w][g][4 * l] =
                (f4){acc[base + g][0], acc[base + g][1], acc[base + g][2], acc[base + g][3]};
        __syncthreads();
        #pragma unroll
        for (int gg = 0; gg < 2; ++gg) {
            int g = 2 * w + gg;
            f4 s = bb2;
            #pragma unroll
            for (int ww = 0; ww < 4; ++ww) {
                f4 r = *(const f4*)&red8[ww][g][4 * l];
                s[0] += r[0]; s[1] += r[1]; s[2] += r[2]; s[3] += r[3];
            }
            float h0 = gelu_f(s[0]), h1v = gelu_f(s[1]),
                  h2v = gelu_f(s[2]), h3v = gelu_f(s[3]);
            float p0 = h0 * w3lo[0] + h1v * w3lo[2] + h2v * w3hi[0] + h3v * w3hi[2];
            float p1 = h0 * w3lo[1] + h1v * w3lo[3] + h2v * w3hi[1] + h3v * w3hi[3];
            #pragma unroll
            for (int off = 1; off < 64; off <<= 1) {
                p0 += __shfl_xor(p0, off);
                p1 += __shfl_xor(p1, off);
            }
            if (l == 0) {
                int row = row0 + base + g;
                mu_tab[row]   = gelu_f(p0 + bb30);
                lmda_tab[row] = expf(-fmaxf(gelu_f(p1 + bb31), 1e-8f));
            }
        }
    }
}

// ---------------------------------------------------------------------------
// Kernel 2: FUSED gather + bwd scan + fwd scan + K-reduction.
// (unchanged from R4 — isolating this round's change to the MLP/pack side)
// ---------------------------------------------------------------------------
__global__ __launch_bounds__(64) void scan_fused_kernel(
    const int* __restrict__ q_id, const float* __restrict__ resp,
    const float* __restrict__ mu_tab, const float* __restrict__ lmda_tab,
    const uint32_t* __restrict__ mask_tab, float* __restrict__ out)
{
    __shared__ float a_lds[64][201];       // stride 201 -> conflict-free
    __shared__ f2 la_lds[4][T_DIM];        // (L1, A) = (1+lmda, mu*lmda)
    __shared__ uint16_t mk_lds[4][T_DIM];
    int tid = threadIdx.x;
    int u0 = blockIdx.x * 4;

    // ---- gather (batched): 800 (ul,t) pairs
    int   qv[13];
    float rv[13];
    #pragma unroll
    for (int p = 0; p < 13; ++p) {
        int idx = tid + 64 * p;
        if (idx < 4 * T_DIM) {
            int ul = idx / T_DIM, t = idx - ul * T_DIM;
            int g = (u0 + ul) * T_DIM + t;
            qv[p] = q_id[g];
            rv[p] = resp[g];
        }
    }
    #pragma unroll
    for (int p = 0; p < 13; ++p) {
        int idx = tid + 64 * p;
        if (idx < 4 * T_DIM) {
            int ul = idx / T_DIM, t = idx - ul * T_DIM;
            int ix = 2 * qv[p] + (rv[p] != 0.0f ? 1 : 0);
            float l  = lmda_tab[ix];
            float mu = mu_tab[ix];
            la_lds[ul][t] = (f2){1.0f + l, mu * l};
            mk_lds[ul][t] = (uint16_t)mask_tab[qv[p]];
        }
    }
    __syncthreads();

    int ul = tid >> 4, k = tid & 15;
    float* ap = a_lds[tid];
    const f2* la = la_lds[ul];
    const uint16_t* mk = mk_lds[ul];

    // ---- backward scan, t = 199..0, 4-deep pipeline (slot j <-> t = tb+j)
    float alpha = 0.0f;
    float L1s0 = la[196][0], L1s1 = la[197][0], L1s2 = la[198][0], L1s3 = la[199][0];
    uint32_t ms0 = mk[196], ms1 = mk[197], ms2 = mk[198], ms3 = mk[199];
    for (int tb = 196; tb >= 0; tb -= 4) {
        int p3 = (tb >= 1) ? tb - 1 : 0;
        int p2 = (tb >= 2) ? tb - 2 : 0;
        int p1 = (tb >= 3) ? tb - 3 : 0;
        int p0 = (tb >= 4) ? tb - 4 : 0;
        { float L1 = L1s3; uint32_t m = ms3; L1s3 = la[p3][0]; ms3 = mk[p3];
          ap[tb + 3] = alpha;
          float an = 1.0f - __builtin_amdgcn_rcpf(L1 + alpha);
          alpha = ((m >> k) & 1) ? an : alpha; }
        { float L1 = L1s2; uint32_t m = ms2; L1s2 = la[p2][0]; ms2 = mk[p2];
          ap[tb + 2] = alpha;
          float an = 1.0f - __builtin_amdgcn_rcpf(L1 + alpha);
          alpha = ((m >> k) & 1) ? an : alpha; }
        { float L1 = L1s1; uint32_t m = ms1; L1s1 = la[p1][0]; ms1 = mk[p1];
          ap[tb + 1] = alpha;
          float an = 1.0f - __builtin_amdgcn_rcpf(L1 + alpha);
          alpha = ((m >> k) & 1) ? an : alpha; }
        { float L1 = L1s0; uint32_t m = ms0; L1s0 = la[p0][0]; ms0 = mk[p0];
          ap[tb + 0] = alpha;
          float an = 1.0f - __builtin_amdgcn_rcpf(L1 + alpha);
          alpha = ((m >> k) & 1) ? an : alpha; }
    }

    // ---- forward scan, t = 0..199, 4-deep pipeline; overwrite ap[t] with
    //      masked ability (fwd writes t<=tb+3 while prefetch reads t>=tb+4).
    float ability = 0.0f;
    f2 lv0 = la[0], lv1 = la[1], lv2 = la[2], lv3 = la[3];
    uint32_t n0 = mk[0], n1 = mk[1], n2 = mk[2], n3 = mk[3];
    float av0 = ap[0], av1 = ap[1], av2 = ap[2], av3 = ap[3];
    for (int tb = 0; tb < 200; tb += 4) {
        int p0 = (tb + 4 < 200) ? tb + 4 : 199;
        int p1 = (tb + 5 < 200) ? tb + 5 : 199;
        int p2 = (tb + 6 < 200) ? tb + 6 : 199;
        int p3 = (tb + 7 < 200) ? tb + 7 : 199;
        { f2 v = lv0; uint32_t m = n0; float a = av0;
          lv0 = la[p0]; n0 = mk[p0]; av0 = ap[p0];
          float r = __builtin_amdgcn_rcpf(v[0] + a);
          float c1 = v[1] + a * a;
          float mt = (ability + c1) * r;
          bool msk = (m >> k) & 1;
          ability = msk ? mt : ability;
          ap[tb + 0] = msk ? ability : 0.0f; }
        { f2 v = lv1; uint32_t m = n1; float a = av1;
          lv1 = la[p1]; n1 = mk[p1]; av1 = ap[p1];
          float r = __builtin_amdgcn_rcpf(v[0] + a);
          float c1 = v[1] + a * a;
          float mt = (ability + c1) * r;
          bool msk = (m >> k) & 1;
          ability = msk ? mt : ability;
          ap[tb + 1] = msk ? ability : 0.0f; }
        { f2 v = lv2; uint32_t m = n2; float a = av2;
          lv2 = la[p2]; n2 = mk[p2]; av2 = ap[p2];
          float r = __builtin_amdgcn_rcpf(v[0] + a);
          float c1 = v[1] + a * a;
          float mt = (ability + c1) * r;
          bool msk = (m >> k) & 1;
          ability = msk ? mt : ability;
          ap[tb + 2] = msk ? ability : 0.0f; }
        { f2 v = lv3; uint32_t m = n3; float a = av3;
          lv3 = la[p3]; n3 = mk[p3]; av3 = ap[p3];
          float r = __builtin_amdgcn_rcpf(v[0] + a);
          float c1 = v[1] + a * a;
          float mt = (ability + c1) * r;
          bool msk = (m >> k) & 1;
          ability = msk ? mt : ability;
          ap[tb + 3] = msk ? ability : 0.0f; }
    }
    __syncthreads();

    // ---- K-reduction, all lanes parallel over the 800 outputs
    #pragma unroll
    for (int p = 0; p < 13; ++p) {
        int idx = tid + 64 * p;
        if (idx < 4 * T_DIM) {
            int uo = idx / T_DIM, t = idx - uo * T_DIM;
            float s = 0.0f;
            #pragma unroll
            for (int kk = 0; kk < 16; ++kk) s += a_lds[uo * 16 + kk][t];
            float c = (float)__popc((unsigned)(mk_lds[uo][t] & 0xffffu));
            out[(u0 + uo) * T_DIM + t] = s * __builtin_amdgcn_rcpf(fmaxf(c, 1e-8f));
        }
    }
}

// ---------------------------------------------------------------------------
extern "C" void kernel_launch(void* const* d_in, const int* in_sizes, int n_in,
                              void* d_out, int out_size, void* d_ws, size_t ws_size,
                              hipStream_t stream) {
    // setup_inputs order: mask, q_id, kmap, resp, diff_mu, disc_mu, W1,b1,W2,b2,W3,b3
    // mask (d_in[0]) is UNUSED by the reference computation.
    const int*     q_id    = (const int*)d_in[1];
    const uint8_t* kmap    = (const uint8_t*)d_in[2];   // layout probed per-block
    const float*   resp    = (const float*)d_in[3];
    const float*   diff_mu = (const float*)d_in[4];
    const float*   disc_mu = (const float*)d_in[5];
    const float*   W1      = (const float*)d_in[6];
    const float*   b1      = (const float*)d_in[7];
    const float*   W2      = (const float*)d_in[8];
    const float*   b2      = (const float*)d_in[9];
    const float*   W3      = (const float*)d_in[10];
    const float*   b3      = (const float*)d_in[11];
    float* out = (float*)d_out;

    char* w = (char*)d_ws;
    float* mu_tab      = (float*)w;      w += (size_t)N_ROWS * 4;
    float* lmda_tab    = (float*)w;      w += (size_t)N_ROWS * 4;
    uint32_t* mask_tab = (uint32_t*)w;   w += (size_t)Q_DIM * 4;

    hipLaunchKernelGGL(mlp_pack_kernel, dim3(N_ROWS / 16), dim3(256), 0, stream,
                       kmap, mask_tab, diff_mu, disc_mu,
                       W1, b1, W2, b2, W3, b3, mu_tab, lmda_tab);
    hipLaunchKernelGGL(scan_fused_kernel, dim3(U_DIM / 4), dim3(64), 0, stream,
                       q_id, resp, mu_tab, lmda_tab, mask_tab, out);
}

// Round 8
// 115.414 us; speedup vs baseline: 2.0858x; 1.0368x over previous
//
#include <hip/hip_runtime.h>
#include <hip/hip_bf16.h>
#include <stdint.h>

// Problem constants (fixed by reference file)
#define U_DIM 2048
#define T_DIM 200
#define Q_DIM 4096
#define K_DIM 16
#define H_DIM 256
#define N_ROWS (Q_DIM * 2)      // 8192 distinct (q, resp) MLP inputs

typedef float f4 __attribute__((ext_vector_type(4)));
typedef float f2 __attribute__((ext_vector_type(2)));
typedef unsigned int u32x4 __attribute__((ext_vector_type(4)));

__device__ __forceinline__ float gelu_f(float x) {
    // exact gelu (approximate=False): 0.5*x*(1+erf(x/sqrt(2)))
    return 0.5f * x * (1.0f + erff(x * 0.70710678118654752440f));
}

// ---------------------------------------------------------------------------
// Kernel 1: fp32 MLP over 8192 rows -> mu_tab, lmda_tab  (+ folded kmap pack)
// (unchanged from R6 — isolating this round's change to the scan kernel)
// ---------------------------------------------------------------------------
__global__ __launch_bounds__(256) void mlp_pack_kernel(
    const uint8_t* __restrict__ kmap, uint32_t* __restrict__ mask_tab,
    const float* __restrict__ diff_mu, const float* __restrict__ disc_mu,
    const float* __restrict__ W1, const float* __restrict__ b1,
    const float* __restrict__ W2, const float* __restrict__ b2,
    const float* __restrict__ W3, const float* __restrict__ b3,
    float* __restrict__ mu_tab, float* __restrict__ lmda_tab)
{
    __shared__ float h1t[H_DIM][20];      // 20 KB: [col i][row g], 16B-aligned rows
    __shared__ float red8[4][8][H_DIM];   // 32 KB: [wave][row g][col j]
    __shared__ uint32_t sflag;
    int tid  = threadIdx.x;
    int bid  = blockIdx.x;
    int row0 = bid * 16;

    // ---- folded kmap pack (blocks 0..15 cover all 4096 q's)
    if (bid < 16) {
        if (tid < 64) {   // probe bool storage: byte-bools vs int32-bools
            const uint32_t* kw = (const uint32_t*)kmap;
            uint32_t any = 0;
            #pragma unroll
            for (int i = 0; i < 16; ++i) any |= (kw[tid + 64 * i] > 1u) ? 1u : 0u;
            uint64_t b = __ballot(any != 0);
            if (tid == 0) sflag = (b != 0) ? 1u : 0u;
        }
        __syncthreads();
        int q = bid * 256 + tid;
        uint32_t m = 0;
        if (sflag) {   // 1 byte per element
            const uint32_t* p = (const uint32_t*)(kmap + (size_t)q * K_DIM);
            #pragma unroll
            for (int w = 0; w < 4; ++w) {
                uint32_t v = p[w];
                #pragma unroll
                for (int b = 0; b < 4; ++b)
                    m |= (((v >> (8 * b)) & 0xffu) ? 1u : 0u) << (4 * w + b);
            }
        } else {       // int32 per element
            const int* ki = (const int*)kmap + (size_t)q * K_DIM;
            #pragma unroll
            for (int k = 0; k < K_DIM; ++k)
                m |= (ki[k] ? 1u : 0u) << k;
        }
        mask_tab[q] = m;
    }

    // ---- layer 1: thread owns col i = tid for all 16 rows
    {
        int i = tid;
        float w1a = W1[i], w1b = W1[H_DIM + i], w1c = W1[2 * H_DIM + i], bi = b1[i];
        float hv[16];
        #pragma unroll
        for (int g = 0; g < 16; ++g) {
            int row = row0 + g;
            float td = diff_mu[row >> 1];
            float ts = disc_mu[row >> 1];
            float rr = (float)(row & 1);
            hv[g] = gelu_f(td * w1a + ts * w1b + rr * w1c + bi);
        }
        *(f4*)&h1t[i][0]  = (f4){hv[0],  hv[1],  hv[2],  hv[3]};
        *(f4*)&h1t[i][4]  = (f4){hv[4],  hv[5],  hv[6],  hv[7]};
        *(f4*)&h1t[i][8]  = (f4){hv[8],  hv[9],  hv[10], hv[11]};
        *(f4*)&h1t[i][12] = (f4){hv[12], hv[13], hv[14], hv[15]};
    }
    __syncthreads();

    // ---- layer 2: wave w owns k in [64w,64w+64); lane l owns cols 4l..4l+3
    int w = tid >> 6, l = tid & 63;
    float acc[16][4];
    #pragma unroll
    for (int g = 0; g < 16; ++g)
        acc[g][0] = acc[g][1] = acc[g][2] = acc[g][3] = 0.0f;
    #pragma unroll 4
    for (int s = 0; s < 64; ++s) {
        int i2 = 64 * w + s;
        f4 wv = *(const f4*)&W2[i2 * H_DIM + 4 * l];
        f4 hA = *(const f4*)&h1t[i2][0];    // wave-uniform addr -> broadcast
        f4 hB = *(const f4*)&h1t[i2][4];
        f4 hC = *(const f4*)&h1t[i2][8];
        f4 hD = *(const f4*)&h1t[i2][12];
        #pragma unroll
        for (int c = 0; c < 4; ++c) {
            acc[0][c]  += hA[0] * wv[c];
            acc[1][c]  += hA[1] * wv[c];
            acc[2][c]  += hA[2] * wv[c];
            acc[3][c]  += hA[3] * wv[c];
            acc[4][c]  += hB[0] * wv[c];
            acc[5][c]  += hB[1] * wv[c];
            acc[6][c]  += hB[2] * wv[c];
            acc[7][c]  += hB[3] * wv[c];
            acc[8][c]  += hC[0] * wv[c];
            acc[9][c]  += hC[1] * wv[c];
            acc[10][c] += hC[2] * wv[c];
            acc[11][c] += hC[3] * wv[c];
            acc[12][c] += hD[0] * wv[c];
            acc[13][c] += hD[1] * wv[c];
            acc[14][c] += hD[2] * wv[c];
            acc[15][c] += hD[3] * wv[c];
        }
    }

    // ---- two 8-row reduce + layer-3 phases; every wave handles 2 rows/phase
    f4 bb2  = *(const f4*)&b2[4 * l];
    f4 w3lo = *(const f4*)&W3[8 * l];        // (j0,c0)(j0,c1)(j1,c0)(j1,c1)
    f4 w3hi = *(const f4*)&W3[8 * l + 4];
    float bb30 = b3[0], bb31 = b3[1];
    #pragma unroll
    for (int phase = 0; phase < 2; ++phase) {
        int base = 8 * phase;
        __syncthreads();
        #pragma unroll
        for (int g = 0; g < 8; ++g)
            *(f4*)&red8[w][g][4 * l] =
                (f4){acc[base + g][0], acc[base + g][1], acc[base + g][2], acc[base + g][3]};
        __syncthreads();
        #pragma unroll
        for (int gg = 0; gg < 2; ++gg) {
            int g = 2 * w + gg;
            f4 s = bb2;
            #pragma unroll
            for (int ww = 0; ww < 4; ++ww) {
                f4 r = *(const f4*)&red8[ww][g][4 * l];
                s[0] += r[0]; s[1] += r[1]; s[2] += r[2]; s[3] += r[3];
            }
            float h0 = gelu_f(s[0]), h1v = gelu_f(s[1]),
                  h2v = gelu_f(s[2]), h3v = gelu_f(s[3]);
            float p0 = h0 * w3lo[0] + h1v * w3lo[2] + h2v * w3hi[0] + h3v * w3hi[2];
            float p1 = h0 * w3lo[1] + h1v * w3lo[3] + h2v * w3hi[1] + h3v * w3hi[3];
            #pragma unroll
            for (int off = 1; off < 64; off <<= 1) {
                p0 += __shfl_xor(p0, off);
                p1 += __shfl_xor(p1, off);
            }
            if (l == 0) {
                int row = row0 + base + g;
                mu_tab[row]   = gelu_f(p0 + bb30);
                lmda_tab[row] = expf(-fmaxf(gelu_f(p1 + bb31), 1e-8f));
            }
        }
    }
}

// ---------------------------------------------------------------------------
// Kernel 2: FUSED gather + bwd scan + fwd scan + K-reduction.
// R7 restructure of both scan loops:
//  - bwd LINEARIZED: alpha = n/d tracked as a pair; masked step is two
//    PARALLEL fmas (n' = fma(l,d,n), d' = fma(L1,d,n)) + cndmask -> the rcp
//    leaves the carried chain (only the stored snapshot alpha_t = n*rcp(d)
//    needs it, off-chain). d grows <= 3^8 per 8-group -> renorm (n*=rcp(d),
//    d=1) once per group; pure representation change, fp32-safe.
//  - 8-wide groups, one-group-ahead prefetch: per 8 iters the LDS traffic is
//    4x ds_read_b128 (la pairs) + 1x ds_read_b128 (8 u16 masks) + 2x
//    ds_write_b128 -> prefetch distance ~8 iters (>120-cyc LDS latency).
//    All reads are 16-lane broadcasts (4 distinct addrs/wave) -> conflict-free.
//  - fwd: r = rcp(L1+a) and cr = (A+a^2)*r computed from prefetched regs
//    off-chain; carried chain = fma + cndmask.
//  - a_lds stride 204 (16B-aligned rows) so all b128 accesses are aligned.
// ---------------------------------------------------------------------------
__global__ __launch_bounds__(64) void scan_fused_kernel(
    const int* __restrict__ q_id, const float* __restrict__ resp,
    const float* __restrict__ mu_tab, const float* __restrict__ lmda_tab,
    const uint32_t* __restrict__ mask_tab, float* __restrict__ out)
{
    __shared__ float a_lds[64][204];       // 52.2 KB, rows 16B-aligned
    __shared__ f2 la_lds[4][T_DIM];        // (L1, A) = (1+lmda, mu*lmda)
    __shared__ uint16_t mk_lds[4][T_DIM];
    int tid = threadIdx.x;
    int u0 = blockIdx.x * 4;

    // ---- gather (batched): 800 (ul,t) pairs
    int   qv[13];
    float rv[13];
    #pragma unroll
    for (int p = 0; p < 13; ++p) {
        int idx = tid + 64 * p;
        if (idx < 4 * T_DIM) {
            int ul = idx / T_DIM, t = idx - ul * T_DIM;
            int g = (u0 + ul) * T_DIM + t;
            qv[p] = q_id[g];
            rv[p] = resp[g];
        }
    }
    #pragma unroll
    for (int p = 0; p < 13; ++p) {
        int idx = tid + 64 * p;
        if (idx < 4 * T_DIM) {
            int ul = idx / T_DIM, t = idx - ul * T_DIM;
            int ix = 2 * qv[p] + (rv[p] != 0.0f ? 1 : 0);
            float l  = lmda_tab[ix];
            float mu = mu_tab[ix];
            la_lds[ul][t] = (f2){1.0f + l, mu * l};
            mk_lds[ul][t] = (uint16_t)mask_tab[qv[p]];
        }
    }
    __syncthreads();

    int ul = tid >> 4, k = tid & 15;
    float* ap = a_lds[tid];
    const f4*    laq = (const f4*)&la_lds[ul][0];    // laq[i] covers t=2i,2i+1
    const u32x4* mkq = (const u32x4*)&mk_lds[ul][0]; // mkq[g] covers t=8g..8g+7

    // ============ backward scan, t = 199..0, 8-wide groups ============
    // group gi covers t = 8gi..8gi+7, processed DESCENDING within group.
    // la mapping: L1[tb+0]=qa[0], L1[tb+1]=qa[2], L1[tb+2]=qb[0], ...,
    //             L1[tb+7]=qd[2]. mask t=tb+2j (lo16) / tb+2j+1 (hi16) of mw[j].
    {
        float n = 0.0f, d = 1.0f;
        f4 qa = laq[96], qb = laq[97], qc = laq[98], qd = laq[99];
        u32x4 mw = mkq[24];
        for (int gi = 24; gi >= 0; --gi) {
            int tb = gi * 8;
            int gp = (gi > 0) ? gi - 1 : 0;
            f4 na = laq[gp * 4 + 0], nb = laq[gp * 4 + 1],
               nc = laq[gp * 4 + 2], nd = laq[gp * 4 + 3];
            u32x4 nw = mkq[gp];
            float at0, at1, at2, at3, at4, at5, at6, at7;
#define BSTEP(L1v, bitexpr, atv) { \
            atv = n * __builtin_amdgcn_rcpf(d); \
            float nn = fmaf((L1v) - 1.0f, d, n); \
            float dd = fmaf((L1v), d, n); \
            bool bb = (bitexpr); \
            n = bb ? nn : n; d = bb ? dd : d; }
            BSTEP(qd[2], (mw[3] >> (16 + k)) & 1, at7)
            BSTEP(qd[0], (mw[3] >> k) & 1, at6)
            BSTEP(qc[2], (mw[2] >> (16 + k)) & 1, at5)
            BSTEP(qc[0], (mw[2] >> k) & 1, at4)
            BSTEP(qb[2], (mw[1] >> (16 + k)) & 1, at3)
            BSTEP(qb[0], (mw[1] >> k) & 1, at2)
            BSTEP(qa[2], (mw[0] >> (16 + k)) & 1, at1)
            BSTEP(qa[0], (mw[0] >> k) & 1, at0)
#undef BSTEP
            *(f4*)&ap[tb]     = (f4){at0, at1, at2, at3};  // incoming alpha == alpha_next[t]
            *(f4*)&ap[tb + 4] = (f4){at4, at5, at6, at7};
            float s = __builtin_amdgcn_rcpf(d);            // renorm: alpha preserved
            n *= s; d = 1.0f;
            qa = na; qb = nb; qc = nc; qd = nd; mw = nw;
        }
    }
    // ap[] re-read only by the same thread; per-wave LDS ordering suffices.

    // ============ forward scan, t = 0..199, 8-wide groups ============
    // Prefetch of group gi+1 reads ap[tb+8..tb+15] BEFORE this group's writes
    // to ap[tb..tb+7] (disjoint, program-order) -> no hazard.
    {
        float ab = 0.0f;
        f4 qa = laq[0], qb = laq[1], qc = laq[2], qd = laq[3];
        u32x4 mw = mkq[0];
        f4 av0 = *(const f4*)&ap[0], av1 = *(const f4*)&ap[4];
        for (int gi = 0; gi < 25; ++gi) {
            int tb = gi * 8;
            int gp = (gi < 24) ? gi + 1 : 24;
            f4 na = laq[gp * 4 + 0], nb = laq[gp * 4 + 1],
               nc = laq[gp * 4 + 2], nd = laq[gp * 4 + 3];
            u32x4 nw = mkq[gp];
            f4 nv0 = *(const f4*)&ap[gp * 8], nv1 = *(const f4*)&ap[gp * 8 + 4];
            float s0, s1, s2, s3, s4, s5, s6, s7;
#define FSTEP(L1v, Av, aval, bitexpr, sv) { \
            float r  = __builtin_amdgcn_rcpf((L1v) + (aval)); \
            float cr = fmaf((aval), (aval), (Av)) * r; \
            float mt = fmaf(ab, r, cr); \
            bool bb = (bitexpr); \
            ab = bb ? mt : ab; \
            sv = bb ? ab : 0.0f; }
            FSTEP(qa[0], qa[1], av0[0], (mw[0] >> k) & 1, s0)
            FSTEP(qa[2], qa[3], av0[1], (mw[0] >> (16 + k)) & 1, s1)
            FSTEP(qb[0], qb[1], av0[2], (mw[1] >> k) & 1, s2)
            FSTEP(qb[2], qb[3], av0[3], (mw[1] >> (16 + k)) & 1, s3)
            FSTEP(qc[0], qc[1], av1[0], (mw[2] >> k) & 1, s4)
            FSTEP(qc[2], qc[3], av1[1], (mw[2] >> (16 + k)) & 1, s5)
            FSTEP(qd[0], qd[1], av1[2], (mw[3] >> k) & 1, s6)
            FSTEP(qd[2], qd[3], av1[3], (mw[3] >> (16 + k)) & 1, s7)
#undef FSTEP
            *(f4*)&ap[tb]     = (f4){s0, s1, s2, s3};      // masked ability
            *(f4*)&ap[tb + 4] = (f4){s4, s5, s6, s7};
            qa = na; qb = nb; qc = nc; qd = nd; mw = nw;
            av0 = nv0; av1 = nv1;
        }
    }
    __syncthreads();

    // ---- K-reduction, all lanes parallel over the 800 outputs
    #pragma unroll
    for (int p = 0; p < 13; ++p) {
        int idx = tid + 64 * p;
        if (idx < 4 * T_DIM) {
            int uo = idx / T_DIM, t = idx - uo * T_DIM;
            float s = 0.0f;
            #pragma unroll
            for (int kk = 0; kk < 16; ++kk) s += a_lds[uo * 16 + kk][t];
            float c = (float)__popc((unsigned)(mk_lds[uo][t] & 0xffffu));
            out[(u0 + uo) * T_DIM + t] = s * __builtin_amdgcn_rcpf(fmaxf(c, 1e-8f));
        }
    }
}

// ---------------------------------------------------------------------------
extern "C" void kernel_launch(void* const* d_in, const int* in_sizes, int n_in,
                              void* d_out, int out_size, void* d_ws, size_t ws_size,
                              hipStream_t stream) {
    // setup_inputs order: mask, q_id, kmap, resp, diff_mu, disc_mu, W1,b1,W2,b2,W3,b3
    // mask (d_in[0]) is UNUSED by the reference computation.
    const int*     q_id    = (const int*)d_in[1];
    const uint8_t* kmap    = (const uint8_t*)d_in[2];   // layout probed per-block
    const float*   resp    = (const float*)d_in[3];
    const float*   diff_mu = (const float*)d_in[4];
    const float*   disc_mu = (const float*)d_in[5];
    const float*   W1      = (const float*)d_in[6];
    const float*   b1      = (const float*)d_in[7];
    const float*   W2      = (const float*)d_in[8];
    const float*   b2      = (const float*)d_in[9];
    const float*   W3      = (const float*)d_in[10];
    const float*   b3      = (const float*)d_in[11];
    float* out = (float*)d_out;

    char* w = (char*)d_ws;
    float* mu_tab      = (float*)w;      w += (size_t)N_ROWS * 4;
    float* lmda_tab    = (float*)w;      w += (size_t)N_ROWS * 4;
    uint32_t* mask_tab = (uint32_t*)w;   w += (size_t)Q_DIM * 4;

    hipLaunchKernelGGL(mlp_pack_kernel, dim3(N_ROWS / 16), dim3(256), 0, stream,
                       kmap, mask_tab, diff_mu, disc_mu,
                       W1, b1, W2, b2, W3, b3, mu_tab, lmda_tab);
    hipLaunchKernelGGL(scan_fused_kernel, dim3(U_DIM / 4), dim3(64), 0, stream,
                       q_id, resp, mu_tab, lmda_tab, mask_tab, out);
}